// Round 3
// baseline (209.202 us; speedup 1.0000x reference)
//
#include <hip/hip_runtime.h>
#include <hip/hip_bf16.h>
#include <math.h>

// Problem constants: B=1, N=512, FN=8, FE=1, E=32, D0=14, 8 frames.
#define NN 512
#define EE 32

typedef short bf16x8 __attribute__((ext_vector_type(8)));
typedef float f32x4  __attribute__((ext_vector_type(4)));

// RNE float->bf16 (bit pattern in a short)
static __device__ __forceinline__ short f2bf(float f) {
    unsigned u = __builtin_bit_cast(unsigned, f);
    u += 0x7fffu + ((u >> 16) & 1u);
    return (short)(u >> 16);
}

// ---------------------------------------------------------------------------
// K1: center + covariance + 3x3 Jacobi eigh (double), writes center[3], V[9]
// ws layout written: ws[0..2]=center, ws[3+r*3+c]=V[r][c] (cols ascending eig)
// ---------------------------------------------------------------------------
__global__ void __launch_bounds__(256) frame_kernel(const float* __restrict__ x,
                                                    float* __restrict__ ws) {
    __shared__ double red[4][9];
    int t = threadIdx.x;
    double s[9] = {0,0,0,0,0,0,0,0,0};
    for (int n = t; n < NN; n += 256) {
        double X = x[n*3+0], Y = x[n*3+1], Z = x[n*3+2];
        s[0]+=X; s[1]+=Y; s[2]+=Z;
        s[3]+=X*X; s[4]+=X*Y; s[5]+=X*Z; s[6]+=Y*Y; s[7]+=Y*Z; s[8]+=Z*Z;
    }
    #pragma unroll
    for (int m = 1; m < 64; m <<= 1) {
        #pragma unroll
        for (int q = 0; q < 9; ++q) s[q] += __shfl_xor(s[q], m);
    }
    int wave = t >> 6, lane = t & 63;
    if (lane == 0) {
        #pragma unroll
        for (int q = 0; q < 9; ++q) red[wave][q] = s[q];
    }
    __syncthreads();
    if (t == 0) {
        double S[9];
        #pragma unroll
        for (int q = 0; q < 9; ++q) S[q] = red[0][q]+red[1][q]+red[2][q]+red[3][q];
        double cx = S[0]/512.0, cy = S[1]/512.0, cz = S[2]/512.0;
        double A[3][3];
        A[0][0]=S[3]-512.0*cx*cx; A[0][1]=S[4]-512.0*cx*cy; A[0][2]=S[5]-512.0*cx*cz;
        A[1][1]=S[6]-512.0*cy*cy; A[1][2]=S[7]-512.0*cy*cz; A[2][2]=S[8]-512.0*cz*cz;
        A[1][0]=A[0][1]; A[2][0]=A[0][2]; A[2][1]=A[1][2];
        double V[3][3] = {{1,0,0},{0,1,0},{0,0,1}};
        for (int sweep = 0; sweep < 8; ++sweep) {
            double off = fabs(A[0][1]) + fabs(A[0][2]) + fabs(A[1][2]);
            double dia = fabs(A[0][0]) + fabs(A[1][1]) + fabs(A[2][2]);
            if (off < 1e-14 * (dia + 1e-300)) break;
            for (int p = 0; p < 3; ++p) for (int q = p+1; q < 3; ++q) {
                double apq = A[p][q];
                if (fabs(apq) < 1e-300) continue;
                double tau = (A[q][q] - A[p][p]) / (2.0 * apq);
                double tt = (tau >= 0 ? 1.0 : -1.0) / (fabs(tau) + sqrt(1.0 + tau*tau));
                double cc = 1.0 / sqrt(1.0 + tt*tt), ss = tt * cc;
                double app = A[p][p], aqq = A[q][q];
                A[p][p] = app - tt * apq;
                A[q][q] = aqq + tt * apq;
                A[p][q] = 0.0; A[q][p] = 0.0;
                for (int k = 0; k < 3; ++k) if (k != p && k != q) {
                    double akp = A[k][p], akq = A[k][q];
                    A[k][p] = cc*akp - ss*akq; A[p][k] = A[k][p];
                    A[k][q] = ss*akp + cc*akq; A[q][k] = A[k][q];
                }
                for (int k = 0; k < 3; ++k) {
                    double vkp = V[k][p], vkq = V[k][q];
                    V[k][p] = cc*vkp - ss*vkq;
                    V[k][q] = ss*vkp + cc*vkq;
                }
            }
        }
        double ev[3] = {A[0][0], A[1][1], A[2][2]};
        int idx[3] = {0,1,2};
        for (int a = 0; a < 2; ++a) for (int b = a+1; b < 3; ++b)
            if (ev[idx[b]] < ev[idx[a]]) { int tmp = idx[a]; idx[a] = idx[b]; idx[b] = tmp; }
        ws[0] = (float)cx; ws[1] = (float)cy; ws[2] = (float)cz;
        for (int r = 0; r < 3; ++r)
            for (int c = 0; c < 3; ++c)
                ws[3 + r*3 + c] = (float)V[r][idx[c]];
    }
}

// ---------------------------------------------------------------------------
// K2 (fused h0 + layer-0 pre): each thread (row=o*512+j, c) rebuilds the 14-dim
// h0 row in registers (cheap, redundant x32), writes H0 (c<14), and the two
// pre-projections PJ/PIB for layer 0.
// ---------------------------------------------------------------------------
__global__ void __launch_bounds__(256) pre0_kernel(const float* __restrict__ x,
                                                   const float* __restrict__ v,
                                                   const float* __restrict__ nf,
                                                   const float* __restrict__ FR,
                                                   const float* __restrict__ ew1,
                                                   const float* __restrict__ eb1,
                                                   float* __restrict__ H0,
                                                   float* __restrict__ PJ,
                                                   float* __restrict__ PIB) {
    int t = blockIdx.x * 256 + threadIdx.x;   // 0..131071
    int c = t & 31, row = t >> 5;             // row = o*512+j
    int o = row >> 9, j = row & 511;
    float hrow[14];
    float xc0 = x[j*3+0] - FR[0], xc1 = x[j*3+1] - FR[1], xc2 = x[j*3+2] - FR[2];
    float v0 = v[j*3+0], v1 = v[j*3+1], v2 = v[j*3+2];
    #pragma unroll
    for (int i = 0; i < 3; ++i) {
        float sgn = ((o >> (2 - i)) & 1) ? -1.f : 1.f;
        float px = FR[3 + 0*3 + i]*xc0 + FR[3 + 1*3 + i]*xc1 + FR[3 + 2*3 + i]*xc2;
        float pv = FR[3 + 0*3 + i]*v0  + FR[3 + 1*3 + i]*v1  + FR[3 + 2*3 + i]*v2;
        hrow[i]     = sgn * px;
        hrow[3 + i] = sgn * pv;
    }
    #pragma unroll
    for (int k = 0; k < 8; ++k) hrow[6 + k] = nf[j*8 + k];
    if (c < 14) H0[row * 14 + c] = hrow[c];
    float pj = 0.f, pi = eb1[c];
    #pragma unroll
    for (int k = 0; k < 14; ++k) {
        pj = fmaf(hrow[k], ew1[(1 + k) * 32 + c], pj);
        pi = fmaf(hrow[k], ew1[(15 + k) * 32 + c], pi);
    }
    PJ[row * 32 + c] = pj;
    PIB[row * 32 + c] = pi;
}

// ---------------------------------------------------------------------------
// K3a (layer 1 pre): PJ/PIB from HA (D=32)
// ---------------------------------------------------------------------------
__global__ void __launch_bounds__(256) pre1_kernel(const float* __restrict__ h,
                                                   const float* __restrict__ ew1,
                                                   const float* __restrict__ eb1,
                                                   float* __restrict__ PJ,
                                                   float* __restrict__ PIB) {
    int t = blockIdx.x * 256 + threadIdx.x;   // 0..131071
    int c = t & 31, row = t >> 5;
    const float* hr = h + row * 32;
    float pj = 0.f, pi = eb1[c];
    #pragma unroll
    for (int k = 0; k < 32; ++k) {
        float hv = hr[k];
        pj = fmaf(hv, ew1[(1 + k) * 32 + c], pj);
        pi = fmaf(hv, ew1[(33 + k) * 32 + c], pi);
    }
    PJ[row * 32 + c] = pj;
    PIB[row * 32 + c] = pi;
}

// ---------------------------------------------------------------------------
// K3b: edge MLP (MFMA) + aggregation + node MLP. ONE BLOCK per (o,i);
// 4 waves j-split (2 tiles of 64 j each), LDS-reduce agg, wave 0 does tail.
//  m1 built per-lane in A-fragment layout: A[m=lane&15][k=(lane>>4)*8+e]
//  B fragment: W2[k=(lane>>4)*8+e][n=lane&15 (+16)]
//  C/D: col=lane&15 (c), row=(lane>>4)*4+reg (j in tile)
// ---------------------------------------------------------------------------
template<int D>
__global__ void __launch_bounds__(256) edge_kernel(
    const float* __restrict__ PJ,      // [8*512][32]
    const float* __restrict__ PIB,     // [8*512][32] (includes +eb1)
    const float* __restrict__ edge,    // [512][512]
    const float* __restrict__ h,       // [8*512][D]
    const float* __restrict__ ew1,     // row 0 = we[32]
    const float* __restrict__ ew2,     // [32][32]
    const float* __restrict__ eb2,
    const float* __restrict__ nw1,     // [D+32][32]
    const float* __restrict__ nb1,
    const float* __restrict__ nw2,     // [32][32]
    const float* __restrict__ nb2,
    float* __restrict__ hout)          // [8*512][32]
{
    const int t = threadIdx.x;
    const int wv = t >> 6, lane = t & 63;
    const int row = blockIdx.x;               // 0..4095 = (o<<9)|i
    const int o = row >> 9, i = row & 511;
    const int l15 = lane & 15;
    const int kbase = (lane >> 4) * 8;        // quad*8

    __shared__ float sAgg[4][32];

    // Hoisted per-lane constants (fp32): pre_i (+eb1) and we for this lane's 8 k's
    f32x4 piA = *(const f32x4*)(PIB + row * 32 + kbase);
    f32x4 piB = *(const f32x4*)(PIB + row * 32 + kbase + 4);
    f32x4 weA = *(const f32x4*)(ew1 + kbase);
    f32x4 weB = *(const f32x4*)(ew1 + kbase + 4);
    float pi_f[8], we_f[8];
    #pragma unroll
    for (int e = 0; e < 4; ++e) {
        pi_f[e] = piA[e]; pi_f[4+e] = piB[e];
        we_f[e] = weA[e]; we_f[4+e] = weB[e];
    }
    // B fragments (W2), loaded once per wave
    bf16x8 bfrag0, bfrag1;
    #pragma unroll
    for (int e = 0; e < 8; ++e) {
        bfrag0[e] = f2bf(ew2[(kbase + e) * 32 + l15]);
        bfrag1[e] = f2bf(ew2[(kbase + e) * 32 + l15 + 16]);
    }
    const float b2v0 = eb2[l15], b2v1 = eb2[l15 + 16];
    float agg0 = 0.f, agg1 = 0.f;

    const float* edge_i = edge + (i << 9);
    const float* pj_o   = PJ + ((size_t)(o << 9)) * 32;

    #pragma unroll
    for (int jj = 0; jj < 2; ++jj) {
        const int jt = (wv << 1) | jj;         // tile 0..7 across 4 waves
        // Build 4 A-fragments (M-tiles of 16 j's each)
        bf16x8 afrag[4];
        #pragma unroll
        for (int jm = 0; jm < 4; ++jm) {
            const int j = (jt << 6) + (jm << 4) + l15;
            const float e_ij = edge_i[j];
            const f32x4 pjA = *(const f32x4*)(pj_o + j * 32 + kbase);
            const f32x4 pjB = *(const f32x4*)(pj_o + j * 32 + kbase + 4);
            #pragma unroll
            for (int e = 0; e < 4; ++e) {
                float m1a = fmaf(e_ij, we_f[e], pjA[e] + pi_f[e]);
                afrag[jm][e] = f2bf(fmaxf(m1a, 0.f));
                float m1b = fmaf(e_ij, we_f[4+e], pjB[e] + pi_f[4+e]);
                afrag[jm][4+e] = f2bf(fmaxf(m1b, 0.f));
            }
        }
        // 8 MFMAs: 4 M-tiles x 2 N-halves; relu + accumulate sum over j
        #pragma unroll
        for (int jm = 0; jm < 4; ++jm) {
            f32x4 c0 = {0.f, 0.f, 0.f, 0.f};
            c0 = __builtin_amdgcn_mfma_f32_16x16x32_bf16(afrag[jm], bfrag0, c0, 0, 0, 0);
            #pragma unroll
            for (int r = 0; r < 4; ++r) agg0 += fmaxf(c0[r] + b2v0, 0.f);
            f32x4 c1 = {0.f, 0.f, 0.f, 0.f};
            c1 = __builtin_amdgcn_mfma_f32_16x16x32_bf16(afrag[jm], bfrag1, c1, 0, 0, 0);
            #pragma unroll
            for (int r = 0; r < 4; ++r) agg1 += fmaxf(c1[r] + b2v1, 0.f);
        }
    }
    // Intra-wave: sum quad partials (rows). Lanes l, l^16, l^32, l^48 share col l15.
    agg0 += __shfl_xor(agg0, 16); agg0 += __shfl_xor(agg0, 32);
    agg1 += __shfl_xor(agg1, 16); agg1 += __shfl_xor(agg1, 32);
    if (lane < 16) { sAgg[wv][l15] = agg0; sAgg[wv][16 + l15] = agg1; }
    __syncthreads();
    if (wv) return;

    // Wave 0: cross-wave reduce + node MLP tail.
    const int c2 = lane & 31;
    float red = sAgg[0][c2] + sAgg[1][c2] + sAgg[2][c2] + sAgg[3][c2];
    const float* hr = h + row * D;            // block-uniform -> scalar loads
    float acc = nb1[c2];
    #pragma unroll
    for (int k = 0; k < D; ++k) acc = fmaf(hr[k], nw1[k * 32 + c2], acc);
    #pragma unroll
    for (int k = 0; k < 32; ++k)
        acc = fmaf(__shfl(red, k, 32), nw1[(D + k) * 32 + c2], acc);
    const float dn = fmaxf(acc, 0.f);
    float outv = nb2[c2];
    #pragma unroll
    for (int k = 0; k < 32; ++k)
        outv = fmaf(__shfl(dn, k, 32), nw2[k * 32 + c2], outv);
    if (lane < 32) hout[row * 32 + c2] = outv;
}

// ---------------------------------------------------------------------------
// K4: fused decoder + h_mean + coef MLP + invert_frame. One block per node n;
// 4 waves each decode 2 frame-rows into LDS, wave 0 finishes.
// ---------------------------------------------------------------------------
__global__ void __launch_bounds__(256) decfinal_kernel(
    const float* __restrict__ h2,
    const float* __restrict__ w1, const float* __restrict__ b1,
    const float* __restrict__ w2,   // [32][6]
    const float* __restrict__ b2,
    const float* __restrict__ x, const float* __restrict__ v,
    const float* __restrict__ FR,
    const float* __restrict__ vw1, const float* __restrict__ vb1,
    const float* __restrict__ vw2, const float* __restrict__ vb2,
    float* __restrict__ out_hmean, float* __restrict__ out_x,
    float* __restrict__ out_v)
{
    const int n = blockIdx.x;                 // 0..511
    const int t = threadIdx.x;
    const int wv = t >> 6, lane = t & 63;
    const int c = lane & 31;
    __shared__ float sSo[8][6];

    #pragma unroll
    for (int q = 0; q < 2; ++q) {
        const int o = (wv << 1) | q;
        const int row = (o << 9) | n;
        float rh = fmaxf(h2[row * 32 + c], 0.f);
        float acc = b1[c];
        #pragma unroll
        for (int k = 0; k < 32; ++k)
            acc = fmaf(__shfl(rh, k, 32), w1[k * 32 + c], acc);
        float s = fmaxf(acc, 0.f);
        #pragma unroll
        for (int m = 0; m < 6; ++m) {
            float p = s * w2[c * 6 + m];
            p += __shfl_xor(p, 1); p += __shfl_xor(p, 2); p += __shfl_xor(p, 4);
            p += __shfl_xor(p, 8); p += __shfl_xor(p, 16);
            if (lane == 0) sSo[o][m] = p + b2[m];
        }
    }
    __syncthreads();
    if (wv) return;

    float hm = 0.f;
    #pragma unroll
    for (int o = 0; o < 8; ++o) hm += h2[((o << 9) | n) * 32 + c];
    hm *= 0.125f;
    if (lane < 32) out_hmean[n * 32 + c] = hm;
    float rh = fmaxf(hm, 0.f);
    float acc = vb1[c];
    #pragma unroll
    for (int k = 0; k < 32; ++k)
        acc = fmaf(__shfl(rh, k, 32), vw1[k * 32 + c], acc);
    float t1 = fmaxf(acc, 0.f);
    float p = t1 * vw2[c];
    p += __shfl_xor(p, 1); p += __shfl_xor(p, 2); p += __shfl_xor(p, 4);
    p += __shfl_xor(p, 8); p += __shfl_xor(p, 16);
    float coef = p + vb2[0];
    if (lane < 3) {
        int i = lane;
        float dx = 0.f, dv = 0.f;
        #pragma unroll
        for (int o = 0; o < 8; ++o) {
            #pragma unroll
            for (int j = 0; j < 3; ++j) {
                float sgn = ((o >> (2 - j)) & 1) ? -1.f : 1.f;
                float f = sgn * FR[3 + i * 3 + j];
                dx = fmaf(f, sSo[o][j], dx);
                dv = fmaf(f, sSo[o][3 + j], dv);
            }
        }
        dx *= 0.125f; dv *= 0.125f;
        float vout = v[n * 3 + i] + dv;
        out_v[n * 3 + i] = vout;
        out_x[n * 3 + i] = x[n * 3 + i] + vout * coef + dx;
    }
}

// ---------------------------------------------------------------------------
extern "C" void kernel_launch(void* const* d_in, const int* in_sizes, int n_in,
                              void* d_out, int out_size, void* d_ws, size_t ws_size,
                              hipStream_t stream) {
    const float* node_feat = (const float*)d_in[0];
    const float* edge      = (const float*)d_in[1];
    const float* x         = (const float*)d_in[2];
    const float* v         = (const float*)d_in[3];
    const float* e0_w1 = (const float*)d_in[4];
    const float* e0_b1 = (const float*)d_in[5];
    const float* e0_w2 = (const float*)d_in[6];
    const float* e0_b2 = (const float*)d_in[7];
    const float* n0_w1 = (const float*)d_in[8];
    const float* n0_b1 = (const float*)d_in[9];
    const float* n0_w2 = (const float*)d_in[10];
    const float* n0_b2 = (const float*)d_in[11];
    const float* e1_w1 = (const float*)d_in[12];
    const float* e1_b1 = (const float*)d_in[13];
    const float* e1_w2 = (const float*)d_in[14];
    const float* e1_b2 = (const float*)d_in[15];
    const float* n1_w1 = (const float*)d_in[16];
    const float* n1_b1 = (const float*)d_in[17];
    const float* n1_w2 = (const float*)d_in[18];
    const float* n1_b2 = (const float*)d_in[19];
    const float* dec_w1 = (const float*)d_in[20];
    const float* dec_b1 = (const float*)d_in[21];
    const float* dec_w2 = (const float*)d_in[22];
    const float* dec_b2 = (const float*)d_in[23];
    const float* vc_w1 = (const float*)d_in[24];
    const float* vc_b1 = (const float*)d_in[25];
    const float* vc_w2 = (const float*)d_in[26];
    const float* vc_b2 = (const float*)d_in[27];

    float* ws  = (float*)d_ws;
    float* out = (float*)d_out;

    float* FR  = ws;                 // 16 floats (center + V)
    float* H0  = ws + 16;            // 8*512*14 = 57344
    float* HA  = H0 + 57344;         // 8*512*32 = 131072
    float* HB  = HA + 131072;        // 131072
    float* PJ  = HB + 131072;        // 131072
    float* PIB = PJ + 131072;        // 131072

    // Output 1: edge_feat passthrough
    hipMemcpyAsync(out + 16384, edge, (size_t)262144 * sizeof(float),
                   hipMemcpyDeviceToDevice, stream);

    frame_kernel<<<1, 256, 0, stream>>>(x, FR);

    // Layer 0 (D=14): fused h0-build + pre-projections
    pre0_kernel<<<512, 256, 0, stream>>>(x, v, node_feat, FR, e0_w1, e0_b1,
                                         H0, PJ, PIB);
    edge_kernel<14><<<4096, 256, 0, stream>>>(PJ, PIB, edge, H0, e0_w1, e0_w2,
                                              e0_b2, n0_w1, n0_b1, n0_w2, n0_b2, HA);
    // Layer 1 (D=32)
    pre1_kernel<<<512, 256, 0, stream>>>(HA, e1_w1, e1_b1, PJ, PIB);
    edge_kernel<32><<<4096, 256, 0, stream>>>(PJ, PIB, edge, HA, e1_w1, e1_w2,
                                              e1_b2, n1_w1, n1_b1, n1_w2, n1_b2, HB);
    // Fused decoder + final
    decfinal_kernel<<<512, 256, 0, stream>>>(HB, dec_w1, dec_b1, dec_w2, dec_b2,
                                             x, v, FR, vc_w1, vc_b1, vc_w2, vc_b2,
                                             out, out + 278528, out + 280064);
}

// Round 4
// 163.445 us; speedup vs baseline: 1.2800x; 1.2800x over previous
//
#include <hip/hip_runtime.h>
#include <hip/hip_bf16.h>
#include <hip/hip_fp16.h>
#include <math.h>

// Problem constants: B=1, N=512, FN=8, FE=1, E=32, D0=14, 8 frames.
#define NN 512

typedef _Float16 f16x8 __attribute__((ext_vector_type(8)));
typedef float    f32x4 __attribute__((ext_vector_type(4)));

// ---------------------------------------------------------------------------
// K1: center + covariance + 3x3 Jacobi eigh (double) on thread 0.
// Wave 1 (threads 64..127) concurrently converts W2/we weights to f16
// fragment layouts (independent of FR).
// FR layout: [0..2]=center, [3+r*3+c]=V[r][c] (cols ascending eig)
// W2F layout: [lane][0..7]=B-frag half0 (n=l15), [8..15]=half1 (n=l15+16),
//             k = (lane>>4)*8 + e
// ---------------------------------------------------------------------------
__global__ void __launch_bounds__(256) frame_kernel(
    const float* __restrict__ x, float* __restrict__ FR,
    const float* __restrict__ e0w1, const float* __restrict__ e1w1,
    const float* __restrict__ e0w2, const float* __restrict__ e1w2,
    _Float16* __restrict__ WEH0, _Float16* __restrict__ WEH1,
    _Float16* __restrict__ W2F0, _Float16* __restrict__ W2F1) {
    __shared__ double red[4][9];
    int t = threadIdx.x;
    double s[9] = {0,0,0,0,0,0,0,0,0};
    for (int n = t; n < NN; n += 256) {
        double X = x[n*3+0], Y = x[n*3+1], Z = x[n*3+2];
        s[0]+=X; s[1]+=Y; s[2]+=Z;
        s[3]+=X*X; s[4]+=X*Y; s[5]+=X*Z; s[6]+=Y*Y; s[7]+=Y*Z; s[8]+=Z*Z;
    }
    #pragma unroll
    for (int m = 1; m < 64; m <<= 1) {
        #pragma unroll
        for (int q = 0; q < 9; ++q) s[q] += __shfl_xor(s[q], m);
    }
    int wave = t >> 6, lane = t & 63;
    if (lane == 0) {
        #pragma unroll
        for (int q = 0; q < 9; ++q) red[wave][q] = s[q];
    }
    __syncthreads();
    // Wave 1: f16 weight conversion (runs concurrently with Jacobi below)
    if (wave == 1) {
        int l15 = lane & 15, kb = (lane >> 4) * 8;
        #pragma unroll
        for (int e = 0; e < 8; ++e) {
            W2F0[lane*16 + e]     = (_Float16)e0w2[(kb+e)*32 + l15];
            W2F0[lane*16 + 8 + e] = (_Float16)e0w2[(kb+e)*32 + l15 + 16];
            W2F1[lane*16 + e]     = (_Float16)e1w2[(kb+e)*32 + l15];
            W2F1[lane*16 + 8 + e] = (_Float16)e1w2[(kb+e)*32 + l15 + 16];
        }
        if (lane < 32) { WEH0[lane] = (_Float16)e0w1[lane]; WEH1[lane] = (_Float16)e1w1[lane]; }
    }
    if (t == 0) {
        double S[9];
        #pragma unroll
        for (int q = 0; q < 9; ++q) S[q] = red[0][q]+red[1][q]+red[2][q]+red[3][q];
        double cx = S[0]/512.0, cy = S[1]/512.0, cz = S[2]/512.0;
        double A[3][3];
        A[0][0]=S[3]-512.0*cx*cx; A[0][1]=S[4]-512.0*cx*cy; A[0][2]=S[5]-512.0*cx*cz;
        A[1][1]=S[6]-512.0*cy*cy; A[1][2]=S[7]-512.0*cy*cz; A[2][2]=S[8]-512.0*cz*cz;
        A[1][0]=A[0][1]; A[2][0]=A[0][2]; A[2][1]=A[1][2];
        double V[3][3] = {{1,0,0},{0,1,0},{0,0,1}};
        for (int sweep = 0; sweep < 8; ++sweep) {
            double off = fabs(A[0][1]) + fabs(A[0][2]) + fabs(A[1][2]);
            double dia = fabs(A[0][0]) + fabs(A[1][1]) + fabs(A[2][2]);
            if (off < 1e-14 * (dia + 1e-300)) break;
            for (int p = 0; p < 3; ++p) for (int q = p+1; q < 3; ++q) {
                double apq = A[p][q];
                if (fabs(apq) < 1e-300) continue;
                double tau = (A[q][q] - A[p][p]) / (2.0 * apq);
                double tt = (tau >= 0 ? 1.0 : -1.0) / (fabs(tau) + sqrt(1.0 + tau*tau));
                double cc = 1.0 / sqrt(1.0 + tt*tt), ss = tt * cc;
                double apq2 = apq;
                A[p][p] = A[p][p] - tt * apq2;
                A[q][q] = A[q][q] + tt * apq2;
                A[p][q] = 0.0; A[q][p] = 0.0;
                for (int k = 0; k < 3; ++k) if (k != p && k != q) {
                    double akp = A[k][p], akq = A[k][q];
                    A[k][p] = cc*akp - ss*akq; A[p][k] = A[k][p];
                    A[k][q] = ss*akp + cc*akq; A[q][k] = A[k][q];
                }
                for (int k = 0; k < 3; ++k) {
                    double vkp = V[k][p], vkq = V[k][q];
                    V[k][p] = cc*vkp - ss*vkq;
                    V[k][q] = ss*vkp + cc*vkq;
                }
            }
        }
        double ev[3] = {A[0][0], A[1][1], A[2][2]};
        int idx[3] = {0,1,2};
        for (int a = 0; a < 2; ++a) for (int b = a+1; b < 3; ++b)
            if (ev[idx[b]] < ev[idx[a]]) { int tmp = idx[a]; idx[a] = idx[b]; idx[b] = tmp; }
        FR[0] = (float)cx; FR[1] = (float)cy; FR[2] = (float)cz;
        for (int r = 0; r < 3; ++r)
            for (int c = 0; c < 3; ++c)
                FR[3 + r*3 + c] = (float)V[r][idx[c]];
    }
}

// ---------------------------------------------------------------------------
// K2 (fused h0 + layer-0 pre): thread (row=o*512+j, c) rebuilds the 14-dim h0
// row in registers, writes H0 (c<14) and f16 pre-projections PJ/PIB.
// ---------------------------------------------------------------------------
__global__ void __launch_bounds__(256) pre0_kernel(const float* __restrict__ x,
                                                   const float* __restrict__ v,
                                                   const float* __restrict__ nf,
                                                   const float* __restrict__ FR,
                                                   const float* __restrict__ ew1,
                                                   const float* __restrict__ eb1,
                                                   float* __restrict__ H0,
                                                   _Float16* __restrict__ PJ,
                                                   _Float16* __restrict__ PIB) {
    int t = blockIdx.x * 256 + threadIdx.x;   // 0..131071
    int c = t & 31, row = t >> 5;             // row = o*512+j
    int o = row >> 9, j = row & 511;
    float hrow[14];
    float xc0 = x[j*3+0] - FR[0], xc1 = x[j*3+1] - FR[1], xc2 = x[j*3+2] - FR[2];
    float v0 = v[j*3+0], v1 = v[j*3+1], v2 = v[j*3+2];
    #pragma unroll
    for (int i = 0; i < 3; ++i) {
        float sgn = ((o >> (2 - i)) & 1) ? -1.f : 1.f;
        float px = FR[3 + 0*3 + i]*xc0 + FR[3 + 1*3 + i]*xc1 + FR[3 + 2*3 + i]*xc2;
        float pv = FR[3 + 0*3 + i]*v0  + FR[3 + 1*3 + i]*v1  + FR[3 + 2*3 + i]*v2;
        hrow[i]     = sgn * px;
        hrow[3 + i] = sgn * pv;
    }
    #pragma unroll
    for (int k = 0; k < 8; ++k) hrow[6 + k] = nf[j*8 + k];
    if (c < 14) H0[row * 14 + c] = hrow[c];
    float pj = 0.f, pi = eb1[c];
    #pragma unroll
    for (int k = 0; k < 14; ++k) {
        pj = fmaf(hrow[k], ew1[(1 + k) * 32 + c], pj);
        pi = fmaf(hrow[k], ew1[(15 + k) * 32 + c], pi);
    }
    PJ[row * 32 + c] = (_Float16)pj;
    PIB[row * 32 + c] = (_Float16)pi;
}

// ---------------------------------------------------------------------------
// K3: edge MLP (f16 MFMA, packed f16 m1-build) + aggregation + node MLP.
// Block = (o, i-pair); wave w: i = i0+(w&1), j-half = w>>1 (4 tiles of 64 j).
// A-frag built directly by v_pk_{add,fma,max}_f16: A[m=lane&15][k=quad*8+e].
// C/D: col=lane&15 (channel), row=quad*4+reg (j in 16-tile).
// Layer-0 variant (NEXT=true) fuses next layer's pre-projection into the tail.
// ---------------------------------------------------------------------------
template<int D, bool NEXT>
__global__ void __launch_bounds__(256, 6) edge_kernel(
    const _Float16* __restrict__ PJH,   // [4096][32] f16
    const _Float16* __restrict__ PIH,   // [4096][32] f16 (includes +eb1)
    const _Float16* __restrict__ WEH,   // [32] f16 (ew1 row 0)
    const _Float16* __restrict__ W2F,   // [64][16] f16 B-fragments
    const float* __restrict__ edge,     // [512][512]
    const float* __restrict__ h,        // [4096][D] f32 (node-MLP input)
    const float* __restrict__ eb2,
    const float* __restrict__ nw1,      // [D+32][32]
    const float* __restrict__ nb1,
    const float* __restrict__ nw2,      // [32][32]
    const float* __restrict__ nb2,
    float* __restrict__ hout,           // [4096][32] f32
    const float* __restrict__ ew1n,     // next-layer e_w1 (NEXT only)
    const float* __restrict__ eb1n,     // next-layer e_b1 (NEXT only)
    _Float16* __restrict__ PJn,         // next-layer PJ f16 (NEXT only)
    _Float16* __restrict__ PIn)         // next-layer PIB f16 (NEXT only)
{
    const int t = threadIdx.x;
    const int wv = t >> 6, lane = t & 63;
    const int o = blockIdx.x >> 8;
    const int i0 = (blockIdx.x & 255) << 1;
    const int i = i0 + (wv & 1);
    const int jh = wv >> 1;
    const int row = (o << 9) | i;
    const int l15 = lane & 15;
    const int kbase = (lane >> 4) * 8;

    __shared__ float sAgg[4][32];

    // Setup: per-wave f16 fragments (3 dwordx4 loads + 2 scalar)
    const f16x8 pi8 = *(const f16x8*)(PIH + row * 32 + kbase);
    const f16x8 we8 = *(const f16x8*)(WEH + kbase);
    const f16x8 bfrag0 = *(const f16x8*)(W2F + lane * 16);
    const f16x8 bfrag1 = *(const f16x8*)(W2F + lane * 16 + 8);
    const float b2v0 = eb2[l15], b2v1 = eb2[l15 + 16];
    const f16x8 z8 = {0,0,0,0,0,0,0,0};
    float agg0 = 0.f, agg1 = 0.f;

    const float* edge_i = edge + (i << 9);
    const _Float16* pj_o = PJH + ((size_t)(o << 9)) * 32;

    #pragma unroll
    for (int jt = 0; jt < 4; ++jt) {
        const int jtbase = ((jh << 2) | jt) << 6;
        #pragma unroll
        for (int jm = 0; jm < 4; ++jm) {
            const int j = jtbase + (jm << 4) + l15;
            const _Float16 eh = (_Float16)edge_i[j];
            const f16x8 e8 = {eh, eh, eh, eh, eh, eh, eh, eh};
            const f16x8 pj8 = *(const f16x8*)(pj_o + j * 32 + kbase);
            f16x8 m = e8 * we8 + (pj8 + pi8);          // v_pk_fma_f16 + v_pk_add_f16
            m = __builtin_elementwise_max(m, z8);      // v_pk_max_f16
            f32x4 c0 = {0.f, 0.f, 0.f, 0.f};
            c0 = __builtin_amdgcn_mfma_f32_16x16x32_f16(m, bfrag0, c0, 0, 0, 0);
            #pragma unroll
            for (int r = 0; r < 4; ++r) agg0 += fmaxf(c0[r] + b2v0, 0.f);
            f32x4 c1 = {0.f, 0.f, 0.f, 0.f};
            c1 = __builtin_amdgcn_mfma_f32_16x16x32_f16(m, bfrag1, c1, 0, 0, 0);
            #pragma unroll
            for (int r = 0; r < 4; ++r) agg1 += fmaxf(c1[r] + b2v1, 0.f);
        }
    }
    // Intra-wave: sum quad partials (C rows). Lanes l, l^16, l^32, l^48 share col l15.
    agg0 += __shfl_xor(agg0, 16); agg0 += __shfl_xor(agg0, 32);
    agg1 += __shfl_xor(agg1, 16); agg1 += __shfl_xor(agg1, 32);
    if (lane < 16) { sAgg[wv][l15] = agg0; sAgg[wv][16 + l15] = agg1; }
    __syncthreads();
    if (wv >= 2) return;

    // Waves 0,1: finish their own i (wave w and w+2 share i).
    const int c2 = lane & 31;
    const float red = sAgg[wv][c2] + sAgg[wv + 2][c2];
    const float* hr = h + row * D;            // wave-uniform base
    float acc = nb1[c2];
    #pragma unroll
    for (int k = 0; k < D; ++k) acc = fmaf(hr[k], nw1[k * 32 + c2], acc);
    #pragma unroll
    for (int k = 0; k < 32; ++k)
        acc = fmaf(__shfl(red, k, 32), nw1[(D + k) * 32 + c2], acc);
    const float dn = fmaxf(acc, 0.f);
    float outv = nb2[c2];
    #pragma unroll
    for (int k = 0; k < 32; ++k)
        outv = fmaf(__shfl(dn, k, 32), nw2[k * 32 + c2], outv);
    if (lane < 32) hout[row * 32 + c2] = outv;

    if (NEXT) {
        // Fused next-layer pre-projection from in-register hout row.
        float pj1 = 0.f, pi1 = eb1n[c2];
        #pragma unroll
        for (int k = 0; k < 32; ++k) {
            const float hk = __shfl(outv, k, 32);
            pj1 = fmaf(hk, ew1n[(1 + k) * 32 + c2], pj1);
            pi1 = fmaf(hk, ew1n[(33 + k) * 32 + c2], pi1);
        }
        if (lane < 32) {
            PJn[row * 32 + c2] = (_Float16)pj1;
            PIn[row * 32 + c2] = (_Float16)pi1;
        }
    }
}

// ---------------------------------------------------------------------------
// K4: fused decoder + h_mean + coef MLP + invert_frame. One block per node n.
// ---------------------------------------------------------------------------
__global__ void __launch_bounds__(256) decfinal_kernel(
    const float* __restrict__ h2,
    const float* __restrict__ w1, const float* __restrict__ b1,
    const float* __restrict__ w2,   // [32][6]
    const float* __restrict__ b2,
    const float* __restrict__ x, const float* __restrict__ v,
    const float* __restrict__ FR,
    const float* __restrict__ vw1, const float* __restrict__ vb1,
    const float* __restrict__ vw2, const float* __restrict__ vb2,
    float* __restrict__ out_hmean, float* __restrict__ out_x,
    float* __restrict__ out_v)
{
    const int n = blockIdx.x;                 // 0..511
    const int t = threadIdx.x;
    const int wv = t >> 6, lane = t & 63;
    const int c = lane & 31;
    __shared__ float sSo[8][6];

    #pragma unroll
    for (int q = 0; q < 2; ++q) {
        const int o = (wv << 1) | q;
        const int row = (o << 9) | n;
        float rh = fmaxf(h2[row * 32 + c], 0.f);
        float acc = b1[c];
        #pragma unroll
        for (int k = 0; k < 32; ++k)
            acc = fmaf(__shfl(rh, k, 32), w1[k * 32 + c], acc);
        float s = fmaxf(acc, 0.f);
        #pragma unroll
        for (int m = 0; m < 6; ++m) {
            float p = s * w2[c * 6 + m];
            p += __shfl_xor(p, 1); p += __shfl_xor(p, 2); p += __shfl_xor(p, 4);
            p += __shfl_xor(p, 8); p += __shfl_xor(p, 16);
            if (lane == 0) sSo[o][m] = p + b2[m];
        }
    }
    __syncthreads();
    if (wv) return;

    float hm = 0.f;
    #pragma unroll
    for (int o = 0; o < 8; ++o) hm += h2[((o << 9) | n) * 32 + c];
    hm *= 0.125f;
    if (lane < 32) out_hmean[n * 32 + c] = hm;
    float rh = fmaxf(hm, 0.f);
    float acc = vb1[c];
    #pragma unroll
    for (int k = 0; k < 32; ++k)
        acc = fmaf(__shfl(rh, k, 32), vw1[k * 32 + c], acc);
    float t1 = fmaxf(acc, 0.f);
    float p = t1 * vw2[c];
    p += __shfl_xor(p, 1); p += __shfl_xor(p, 2); p += __shfl_xor(p, 4);
    p += __shfl_xor(p, 8); p += __shfl_xor(p, 16);
    float coef = p + vb2[0];
    if (lane < 3) {
        int i = lane;
        float dx = 0.f, dv = 0.f;
        #pragma unroll
        for (int o = 0; o < 8; ++o) {
            #pragma unroll
            for (int j = 0; j < 3; ++j) {
                float sgn = ((o >> (2 - j)) & 1) ? -1.f : 1.f;
                float f = sgn * FR[3 + i * 3 + j];
                dx = fmaf(f, sSo[o][j], dx);
                dv = fmaf(f, sSo[o][3 + j], dv);
            }
        }
        dx *= 0.125f; dv *= 0.125f;
        float vout = v[n * 3 + i] + dv;
        out_v[n * 3 + i] = vout;
        out_x[n * 3 + i] = x[n * 3 + i] + vout * coef + dx;
    }
}

// ---------------------------------------------------------------------------
extern "C" void kernel_launch(void* const* d_in, const int* in_sizes, int n_in,
                              void* d_out, int out_size, void* d_ws, size_t ws_size,
                              hipStream_t stream) {
    const float* node_feat = (const float*)d_in[0];
    const float* edge      = (const float*)d_in[1];
    const float* x         = (const float*)d_in[2];
    const float* v         = (const float*)d_in[3];
    const float* e0_w1 = (const float*)d_in[4];
    const float* e0_b1 = (const float*)d_in[5];
    const float* e0_w2 = (const float*)d_in[6];
    const float* e0_b2 = (const float*)d_in[7];
    const float* n0_w1 = (const float*)d_in[8];
    const float* n0_b1 = (const float*)d_in[9];
    const float* n0_w2 = (const float*)d_in[10];
    const float* n0_b2 = (const float*)d_in[11];
    const float* e1_w1 = (const float*)d_in[12];
    const float* e1_b1 = (const float*)d_in[13];
    const float* e1_w2 = (const float*)d_in[14];
    const float* e1_b2 = (const float*)d_in[15];
    const float* n1_w1 = (const float*)d_in[16];
    const float* n1_b1 = (const float*)d_in[17];
    const float* n1_w2 = (const float*)d_in[18];
    const float* n1_b2 = (const float*)d_in[19];
    const float* dec_w1 = (const float*)d_in[20];
    const float* dec_b1 = (const float*)d_in[21];
    const float* dec_w2 = (const float*)d_in[22];
    const float* dec_b2 = (const float*)d_in[23];
    const float* vc_w1 = (const float*)d_in[24];
    const float* vc_b1 = (const float*)d_in[25];
    const float* vc_w2 = (const float*)d_in[26];
    const float* vc_b2 = (const float*)d_in[27];

    char* wsb = (char*)d_ws;
    float* out = (float*)d_out;

    float*    FR   = (float*)wsb;                       // 64 B (16 f32)
    float*    H0   = (float*)(wsb + 256);               // 57344 f32
    float*    HA   = (float*)(wsb + 256 + 229376);      // 131072 f32
    float*    HB   = (float*)(wsb + 256 + 229376 + 524288);
    char*     p    = wsb + 256 + 229376 + 524288 + 524288;
    _Float16* PJH0 = (_Float16*)p;            p += 262144;   // 131072 f16
    _Float16* PIH0 = (_Float16*)p;            p += 262144;
    _Float16* PJH1 = (_Float16*)p;            p += 262144;
    _Float16* PIH1 = (_Float16*)p;            p += 262144;
    _Float16* WEH0 = (_Float16*)p;            p += 256;
    _Float16* WEH1 = (_Float16*)p;            p += 256;
    _Float16* W2F0 = (_Float16*)p;            p += 2048;
    _Float16* W2F1 = (_Float16*)p;            p += 2048;

    // Output 1: edge_feat passthrough (SDMA, overlaps with compute)
    hipMemcpyAsync(out + 16384, edge, (size_t)262144 * sizeof(float),
                   hipMemcpyDeviceToDevice, stream);

    frame_kernel<<<1, 256, 0, stream>>>(x, FR, e0_w1, e1_w1, e0_w2, e1_w2,
                                        WEH0, WEH1, W2F0, W2F1);

    // Layer 0 (D=14): fused h0-build + pre-projections (f16)
    pre0_kernel<<<512, 256, 0, stream>>>(x, v, node_feat, FR, e0_w1, e0_b1,
                                         H0, PJH0, PIH0);
    edge_kernel<14, true><<<2048, 256, 0, stream>>>(
        PJH0, PIH0, WEH0, W2F0, edge, H0, e0_b2, n0_w1, n0_b1, n0_w2, n0_b2,
        HA, e1_w1, e1_b1, PJH1, PIH1);
    // Layer 1 (D=32): pre-projection already fused into layer 0's tail
    edge_kernel<32, false><<<2048, 256, 0, stream>>>(
        PJH1, PIH1, WEH1, W2F1, edge, HA, e1_b2, n1_w1, n1_b1, n1_w2, n1_b2,
        HB, nullptr, nullptr, nullptr, nullptr);
    // Fused decoder + final
    decfinal_kernel<<<512, 256, 0, stream>>>(HB, dec_w1, dec_b1, dec_w2, dec_b2,
                                             x, v, FR, vc_w1, vc_b1, vc_w2, vc_b2,
                                             out, out + 278528, out + 280064);
}

// Round 5
// 154.760 us; speedup vs baseline: 1.3518x; 1.0561x over previous
//
#include <hip/hip_runtime.h>
#include <hip/hip_bf16.h>
#include <hip/hip_fp16.h>
#include <math.h>

// Problem constants: B=1, N=512, FN=8, FE=1, E=32, D0=14, 8 frames.
#define NN 512

typedef _Float16 f16x8 __attribute__((ext_vector_type(8)));
typedef float    f32x4 __attribute__((ext_vector_type(4)));

// ---------------------------------------------------------------------------
// Device helper: covariance reduction + 3x3 Jacobi eigh (double).
// Every block runs this redundantly (bitwise-identical result) -> no extra
// dispatch, no cross-block dependency. Result left in sFR[12]:
// [0..2]=center, [3+r*3+c]=V[r][c], eigen-cols ascending.
// ---------------------------------------------------------------------------
__device__ __forceinline__ void compute_frame(const float* __restrict__ x,
                                              float* __restrict__ sFR,
                                              double (*red)[9]) {
    const int t = threadIdx.x;
    double s[9] = {0,0,0,0,0,0,0,0,0};
    for (int n = t; n < NN; n += 256) {
        double X = x[n*3+0], Y = x[n*3+1], Z = x[n*3+2];
        s[0]+=X; s[1]+=Y; s[2]+=Z;
        s[3]+=X*X; s[4]+=X*Y; s[5]+=X*Z; s[6]+=Y*Y; s[7]+=Y*Z; s[8]+=Z*Z;
    }
    #pragma unroll
    for (int m = 1; m < 64; m <<= 1) {
        #pragma unroll
        for (int q = 0; q < 9; ++q) s[q] += __shfl_xor(s[q], m);
    }
    const int wave = t >> 6, lane = t & 63;
    if (lane == 0) {
        #pragma unroll
        for (int q = 0; q < 9; ++q) red[wave][q] = s[q];
    }
    __syncthreads();
    if (t == 0) {
        double S[9];
        #pragma unroll
        for (int q = 0; q < 9; ++q) S[q] = red[0][q]+red[1][q]+red[2][q]+red[3][q];
        double cx = S[0]/512.0, cy = S[1]/512.0, cz = S[2]/512.0;
        double A[3][3];
        A[0][0]=S[3]-512.0*cx*cx; A[0][1]=S[4]-512.0*cx*cy; A[0][2]=S[5]-512.0*cx*cz;
        A[1][1]=S[6]-512.0*cy*cy; A[1][2]=S[7]-512.0*cy*cz; A[2][2]=S[8]-512.0*cz*cz;
        A[1][0]=A[0][1]; A[2][0]=A[0][2]; A[2][1]=A[1][2];
        double V[3][3] = {{1,0,0},{0,1,0},{0,0,1}};
        for (int sweep = 0; sweep < 8; ++sweep) {
            double off = fabs(A[0][1]) + fabs(A[0][2]) + fabs(A[1][2]);
            double dia = fabs(A[0][0]) + fabs(A[1][1]) + fabs(A[2][2]);
            if (off < 1e-14 * (dia + 1e-300)) break;
            for (int p = 0; p < 3; ++p) for (int q = p+1; q < 3; ++q) {
                double apq = A[p][q];
                if (fabs(apq) < 1e-300) continue;
                double tau = (A[q][q] - A[p][p]) / (2.0 * apq);
                double tt = (tau >= 0 ? 1.0 : -1.0) / (fabs(tau) + sqrt(1.0 + tau*tau));
                double cc = 1.0 / sqrt(1.0 + tt*tt), ss = tt * cc;
                A[p][p] = A[p][p] - tt * apq;
                A[q][q] = A[q][q] + tt * apq;
                A[p][q] = 0.0; A[q][p] = 0.0;
                for (int k = 0; k < 3; ++k) if (k != p && k != q) {
                    double akp = A[k][p], akq = A[k][q];
                    A[k][p] = cc*akp - ss*akq; A[p][k] = A[k][p];
                    A[k][q] = ss*akp + cc*akq; A[q][k] = A[k][q];
                }
                for (int k = 0; k < 3; ++k) {
                    double vkp = V[k][p], vkq = V[k][q];
                    V[k][p] = cc*vkp - ss*vkq;
                    V[k][q] = ss*vkp + cc*vkq;
                }
            }
        }
        double ev[3] = {A[0][0], A[1][1], A[2][2]};
        int idx[3] = {0,1,2};
        for (int a = 0; a < 2; ++a) for (int b = a+1; b < 3; ++b)
            if (ev[idx[b]] < ev[idx[a]]) { int tmp = idx[a]; idx[a] = idx[b]; idx[b] = tmp; }
        sFR[0] = (float)cx; sFR[1] = (float)cy; sFR[2] = (float)cz;
        for (int r = 0; r < 3; ++r)
            for (int c = 0; c < 3; ++c)
                sFR[3 + r*3 + c] = (float)V[r][idx[c]];
    }
    __syncthreads();
}

// ---------------------------------------------------------------------------
// K1 (fused frame + h0 + layer-0 pre + weight-convert + edge passthrough):
// 512 blocks x 256 thr. Block b handles rows b*8..b*8+7 (row = o*512+j),
// thread = (row, c). PJ written FRAGMENT-MAJOR (PJF):
//   PJF[((o*32 + (j>>4))*64 + ((j&15)|((c>>3)<<4)))*8 + (c&7)]
// so edge_kernel reads one contiguous 1 KB chunk per wave per j-tile.
// ---------------------------------------------------------------------------
__global__ void __launch_bounds__(256) pre0_kernel(
    const float* __restrict__ x, const float* __restrict__ v,
    const float* __restrict__ nf,
    const float* __restrict__ e0w1, const float* __restrict__ e0b1,
    const float* __restrict__ e0w2, const float* __restrict__ e1w1,
    const float* __restrict__ e1w2,
    const float* __restrict__ edge,
    float* __restrict__ FRg, float* __restrict__ H0,
    _Float16* __restrict__ PJF, _Float16* __restrict__ PIH,
    _Float16* __restrict__ WEH0, _Float16* __restrict__ WEH1,
    _Float16* __restrict__ W2F0, _Float16* __restrict__ W2F1,
    float* __restrict__ out_edge)
{
    __shared__ double red[4][9];
    __shared__ float sFR[12];
    const int t = threadIdx.x;
    const int b = blockIdx.x;

    compute_frame(x, sFR, red);

    // Edge passthrough: 2 floats per thread, fully coalesced.
    ((float2*)out_edge)[b * 256 + t] = ((const float2*)edge)[b * 256 + t];

    // Block 0 extras: publish FR, convert weights to f16 fragment layouts.
    if (b == 0) {
        const int lane = t & 63, wv = t >> 6;
        if (t < 12) FRg[t] = sFR[t];
        const int l15 = lane & 15, kb = (lane >> 4) * 8;
        if (wv == 1) {
            #pragma unroll
            for (int e = 0; e < 8; ++e) {
                W2F0[lane*16 + e]     = (_Float16)e0w2[(kb+e)*32 + l15];
                W2F0[lane*16 + 8 + e] = (_Float16)e0w2[(kb+e)*32 + l15 + 16];
            }
        } else if (wv == 2) {
            #pragma unroll
            for (int e = 0; e < 8; ++e) {
                W2F1[lane*16 + e]     = (_Float16)e1w2[(kb+e)*32 + l15];
                W2F1[lane*16 + 8 + e] = (_Float16)e1w2[(kb+e)*32 + l15 + 16];
            }
        } else if (wv == 3 && lane < 32) {
            WEH0[lane] = (_Float16)e0w1[lane];
            WEH1[lane] = (_Float16)e1w1[lane];
        }
    }

    // Main: h0 row rebuild + layer-0 pre-projections.
    const int c = t & 31;
    const int row = b * 8 + (t >> 5);
    const int o = row >> 9, j = row & 511;
    float hrow[14];
    float xc0 = x[j*3+0] - sFR[0], xc1 = x[j*3+1] - sFR[1], xc2 = x[j*3+2] - sFR[2];
    float v0 = v[j*3+0], v1 = v[j*3+1], v2 = v[j*3+2];
    #pragma unroll
    for (int i = 0; i < 3; ++i) {
        float sgn = ((o >> (2 - i)) & 1) ? -1.f : 1.f;
        float px = sFR[3 + 0*3 + i]*xc0 + sFR[3 + 1*3 + i]*xc1 + sFR[3 + 2*3 + i]*xc2;
        float pv = sFR[3 + 0*3 + i]*v0  + sFR[3 + 1*3 + i]*v1  + sFR[3 + 2*3 + i]*v2;
        hrow[i]     = sgn * px;
        hrow[3 + i] = sgn * pv;
    }
    #pragma unroll
    for (int k = 0; k < 8; ++k) hrow[6 + k] = nf[j*8 + k];
    if (c < 14) H0[row * 14 + c] = hrow[c];
    float pj = 0.f, pi = e0b1[c];
    #pragma unroll
    for (int k = 0; k < 14; ++k) {
        pj = fmaf(hrow[k], e0w1[(1 + k) * 32 + c], pj);
        pi = fmaf(hrow[k], e0w1[(15 + k) * 32 + c], pi);
    }
    PIH[row * 32 + c] = (_Float16)pi;
    const int fl = (j & 15) | ((c >> 3) << 4);
    PJF[(((o << 5) + (j >> 4)) * 64 + fl) * 8 + (c & 7)] = (_Float16)pj;
}

// ---------------------------------------------------------------------------
// K2: edge MLP (f16 MFMA) + aggregation + node MLP.
// Block = (o, i-pair); wave w: i = i0+(w&1), j-half = w>>1 (16 j-tiles each).
// PJF fragment-major: wave's tile load = contiguous dwordx4/lane (1 KB/wave).
// A-frag via v_pk ops: A[m=lane&15][k=(lane>>4)*8+e]; C/D col=lane&15,
// row=quad*4+reg. NEXT fuses next layer's pre-projection into the tail.
// ---------------------------------------------------------------------------
template<int D, bool NEXT>
__global__ void __launch_bounds__(256, 4) edge_kernel(
    const _Float16* __restrict__ PJF,   // [8][32][64][8] f16 fragment-major
    const _Float16* __restrict__ PIH,   // [4096][32] f16 (includes +eb1)
    const _Float16* __restrict__ WEH,   // [32] f16
    const _Float16* __restrict__ W2F,   // [64][16] f16 B-fragments
    const float* __restrict__ edge,     // [512][512]
    const float* __restrict__ h,        // [4096][D] f32
    const float* __restrict__ eb2,
    const float* __restrict__ nw1,      // [D+32][32]
    const float* __restrict__ nb1,
    const float* __restrict__ nw2,      // [32][32]
    const float* __restrict__ nb2,
    float* __restrict__ hout,           // [4096][32] f32
    const float* __restrict__ ew1n,
    const float* __restrict__ eb1n,
    _Float16* __restrict__ PJFn,
    _Float16* __restrict__ PIn)
{
    const int t = threadIdx.x;
    const int wv = t >> 6, lane = t & 63;
    const int o = blockIdx.x >> 8;
    const int i0 = (blockIdx.x & 255) << 1;
    const int i = i0 + (wv & 1);
    const int jh = wv >> 1;
    const int row = (o << 9) | i;
    const int l15 = lane & 15;
    const int kbase = (lane >> 4) * 8;

    __shared__ float sAgg[4][32];

    const f16x8 pi8 = *(const f16x8*)(PIH + row * 32 + kbase);
    const f16x8 we8 = *(const f16x8*)(WEH + kbase);
    const f16x8 bfrag0 = *(const f16x8*)(W2F + lane * 16);
    const f16x8 bfrag1 = *(const f16x8*)(W2F + lane * 16 + 8);
    const float b2v0 = eb2[l15], b2v1 = eb2[l15 + 16];
    const f16x8 z8 = {0,0,0,0,0,0,0,0};
    float agg0 = 0.f, agg1 = 0.f;

    const float* edge_i = edge + (i << 9);
    const _Float16* pjf_o = PJF + (size_t)o * 16384;   // 32 tiles * 512

    #pragma unroll
    for (int jm = 0; jm < 16; ++jm) {
        const int tile = (jh << 4) | jm;
        const f16x8 pj8 = *(const f16x8*)(pjf_o + (tile * 64 + lane) * 8);
        const _Float16 eh = (_Float16)edge_i[tile * 16 + l15];
        const f16x8 e8 = {eh, eh, eh, eh, eh, eh, eh, eh};
        f16x8 m = e8 * we8 + (pj8 + pi8);          // v_pk_fma_f16 + v_pk_add_f16
        m = __builtin_elementwise_max(m, z8);      // v_pk_max_f16
        f32x4 c0 = {0.f, 0.f, 0.f, 0.f};
        c0 = __builtin_amdgcn_mfma_f32_16x16x32_f16(m, bfrag0, c0, 0, 0, 0);
        #pragma unroll
        for (int r = 0; r < 4; ++r) agg0 += fmaxf(c0[r] + b2v0, 0.f);
        f32x4 c1 = {0.f, 0.f, 0.f, 0.f};
        c1 = __builtin_amdgcn_mfma_f32_16x16x32_f16(m, bfrag1, c1, 0, 0, 0);
        #pragma unroll
        for (int r = 0; r < 4; ++r) agg1 += fmaxf(c1[r] + b2v1, 0.f);
    }
    // Sum quad partials (C rows): lanes l, l^16, l^32, l^48 share col l15.
    agg0 += __shfl_xor(agg0, 16); agg0 += __shfl_xor(agg0, 32);
    agg1 += __shfl_xor(agg1, 16); agg1 += __shfl_xor(agg1, 32);
    if (lane < 16) { sAgg[wv][l15] = agg0; sAgg[wv][16 + l15] = agg1; }
    __syncthreads();
    if (wv >= 2) return;

    // Waves 0,1 finish their own i (waves w and w+2 share i).
    const int c2 = lane & 31;
    const float red2 = sAgg[wv][c2] + sAgg[wv + 2][c2];
    const float* hr = h + row * D;            // wave-uniform base
    float acc = nb1[c2];
    #pragma unroll
    for (int k = 0; k < D; ++k) acc = fmaf(hr[k], nw1[k * 32 + c2], acc);
    #pragma unroll
    for (int k = 0; k < 32; ++k)
        acc = fmaf(__shfl(red2, k, 32), nw1[(D + k) * 32 + c2], acc);
    const float dn = fmaxf(acc, 0.f);
    float outv = nb2[c2];
    #pragma unroll
    for (int k = 0; k < 32; ++k)
        outv = fmaf(__shfl(dn, k, 32), nw2[k * 32 + c2], outv);
    if (lane < 32) hout[row * 32 + c2] = outv;

    if (NEXT) {
        float pj1 = 0.f, pi1 = eb1n[c2];
        #pragma unroll
        for (int k = 0; k < 32; ++k) {
            const float hk = __shfl(outv, k, 32);
            pj1 = fmaf(hk, ew1n[(1 + k) * 32 + c2], pj1);
            pi1 = fmaf(hk, ew1n[(33 + k) * 32 + c2], pi1);
        }
        if (lane < 32) {
            PIn[row * 32 + c2] = (_Float16)pi1;
            const int fl = (i & 15) | ((c2 >> 3) << 4);
            PJFn[(((o << 5) + (i >> 4)) * 64 + fl) * 8 + (c2 & 7)] = (_Float16)pj1;
        }
    }
}

// ---------------------------------------------------------------------------
// K3: fused decoder + h_mean + coef MLP + invert_frame. One block per node n.
// ---------------------------------------------------------------------------
__global__ void __launch_bounds__(256) decfinal_kernel(
    const float* __restrict__ h2,
    const float* __restrict__ w1, const float* __restrict__ b1,
    const float* __restrict__ w2,   // [32][6]
    const float* __restrict__ b2,
    const float* __restrict__ x, const float* __restrict__ v,
    const float* __restrict__ FR,
    const float* __restrict__ vw1, const float* __restrict__ vb1,
    const float* __restrict__ vw2, const float* __restrict__ vb2,
    float* __restrict__ out_hmean, float* __restrict__ out_x,
    float* __restrict__ out_v)
{
    const int n = blockIdx.x;                 // 0..511
    const int t = threadIdx.x;
    const int wv = t >> 6, lane = t & 63;
    const int c = lane & 31;
    __shared__ float sSo[8][6];

    #pragma unroll
    for (int q = 0; q < 2; ++q) {
        const int o = (wv << 1) | q;
        const int row = (o << 9) | n;
        float rh = fmaxf(h2[row * 32 + c], 0.f);
        float acc = b1[c];
        #pragma unroll
        for (int k = 0; k < 32; ++k)
            acc = fmaf(__shfl(rh, k, 32), w1[k * 32 + c], acc);
        float s = fmaxf(acc, 0.f);
        #pragma unroll
        for (int m = 0; m < 6; ++m) {
            float p = s * w2[c * 6 + m];
            p += __shfl_xor(p, 1); p += __shfl_xor(p, 2); p += __shfl_xor(p, 4);
            p += __shfl_xor(p, 8); p += __shfl_xor(p, 16);
            if (lane == 0) sSo[o][m] = p + b2[m];
        }
    }
    __syncthreads();
    if (wv) return;

    float hm = 0.f;
    #pragma unroll
    for (int o = 0; o < 8; ++o) hm += h2[((o << 9) | n) * 32 + c];
    hm *= 0.125f;
    if (lane < 32) out_hmean[n * 32 + c] = hm;
    float rh = fmaxf(hm, 0.f);
    float acc = vb1[c];
    #pragma unroll
    for (int k = 0; k < 32; ++k)
        acc = fmaf(__shfl(rh, k, 32), vw1[k * 32 + c], acc);
    float t1 = fmaxf(acc, 0.f);
    float p = t1 * vw2[c];
    p += __shfl_xor(p, 1); p += __shfl_xor(p, 2); p += __shfl_xor(p, 4);
    p += __shfl_xor(p, 8); p += __shfl_xor(p, 16);
    float coef = p + vb2[0];
    if (lane < 3) {
        int i = lane;
        float dx = 0.f, dv = 0.f;
        #pragma unroll
        for (int o = 0; o < 8; ++o) {
            #pragma unroll
            for (int j = 0; j < 3; ++j) {
                float sgn = ((o >> (2 - j)) & 1) ? -1.f : 1.f;
                float f = sgn * FR[3 + i * 3 + j];
                dx = fmaf(f, sSo[o][j], dx);
                dv = fmaf(f, sSo[o][3 + j], dv);
            }
        }
        dx *= 0.125f; dv *= 0.125f;
        float vout = v[n * 3 + i] + dv;
        out_v[n * 3 + i] = vout;
        out_x[n * 3 + i] = x[n * 3 + i] + vout * coef + dx;
    }
}

// ---------------------------------------------------------------------------
extern "C" void kernel_launch(void* const* d_in, const int* in_sizes, int n_in,
                              void* d_out, int out_size, void* d_ws, size_t ws_size,
                              hipStream_t stream) {
    const float* node_feat = (const float*)d_in[0];
    const float* edge      = (const float*)d_in[1];
    const float* x         = (const float*)d_in[2];
    const float* v         = (const float*)d_in[3];
    const float* e0_w1 = (const float*)d_in[4];
    const float* e0_b1 = (const float*)d_in[5];
    const float* e0_w2 = (const float*)d_in[6];
    const float* e0_b2 = (const float*)d_in[7];
    const float* n0_w1 = (const float*)d_in[8];
    const float* n0_b1 = (const float*)d_in[9];
    const float* n0_w2 = (const float*)d_in[10];
    const float* n0_b2 = (const float*)d_in[11];
    const float* e1_w1 = (const float*)d_in[12];
    const float* e1_b1 = (const float*)d_in[13];
    const float* e1_w2 = (const float*)d_in[14];
    const float* e1_b2 = (const float*)d_in[15];
    const float* n1_w1 = (const float*)d_in[16];
    const float* n1_b1 = (const float*)d_in[17];
    const float* n1_w2 = (const float*)d_in[18];
    const float* n1_b2 = (const float*)d_in[19];
    const float* dec_w1 = (const float*)d_in[20];
    const float* dec_b1 = (const float*)d_in[21];
    const float* dec_w2 = (const float*)d_in[22];
    const float* dec_b2 = (const float*)d_in[23];
    const float* vc_w1 = (const float*)d_in[24];
    const float* vc_b1 = (const float*)d_in[25];
    const float* vc_w2 = (const float*)d_in[26];
    const float* vc_b2 = (const float*)d_in[27];

    char* wsb = (char*)d_ws;
    float* out = (float*)d_out;

    float*    FR   = (float*)wsb;                            // 12 f32
    float*    H0   = (float*)(wsb + 256);                    // 57344 f32
    float*    HA   = (float*)(wsb + 256 + 229376);           // 131072 f32
    float*    HB   = (float*)(wsb + 256 + 229376 + 524288);  // 131072 f32
    char*     p    = wsb + 256 + 229376 + 524288 + 524288;
    _Float16* PJF0 = (_Float16*)p;            p += 262144;   // 131072 f16
    _Float16* PIH0 = (_Float16*)p;            p += 262144;
    _Float16* PJF1 = (_Float16*)p;            p += 262144;
    _Float16* PIH1 = (_Float16*)p;            p += 262144;
    _Float16* WEH0 = (_Float16*)p;            p += 256;
    _Float16* WEH1 = (_Float16*)p;            p += 256;
    _Float16* W2F0 = (_Float16*)p;            p += 2048;
    _Float16* W2F1 = (_Float16*)p;            p += 2048;

    // K1: frame (per-block redundant) + h0 + layer-0 pre + weights + passthrough
    pre0_kernel<<<512, 256, 0, stream>>>(x, v, node_feat,
                                         e0_w1, e0_b1, e0_w2, e1_w1, e1_w2,
                                         edge, FR, H0, PJF0, PIH0,
                                         WEH0, WEH1, W2F0, W2F1, out + 16384);
    // K2: layer 0 (D=14), fuses layer-1 pre-projection
    edge_kernel<14, true><<<2048, 256, 0, stream>>>(
        PJF0, PIH0, WEH0, W2F0, edge, H0, e0_b2, n0_w1, n0_b1, n0_w2, n0_b2,
        HA, e1_w1, e1_b1, PJF1, PIH1);
    // K2': layer 1 (D=32)
    edge_kernel<32, false><<<2048, 256, 0, stream>>>(
        PJF1, PIH1, WEH1, W2F1, edge, HA, e1_b2, n1_w1, n1_b1, n1_w2, n1_b2,
        HB, nullptr, nullptr, nullptr, nullptr);
    // K3: decoder + outputs
    decfinal_kernel<<<512, 256, 0, stream>>>(HB, dec_w1, dec_b1, dec_w2, dec_b2,
                                             x, v, FR, vc_w1, vc_b1, vc_w2, vc_b2,
                                             out, out + 278528, out + 280064);
}